// Round 6
// baseline (295.541 us; speedup 1.0000x reference)
//
#include <hip/hip_runtime.h>
#include <hip/hip_bf16.h>

// ---------------------------------------------------------------------------
// GCN 2-layer + edge dot logits, CSR-pull aggregation.
// agg[d] = dinv[d] * ( sum_{s in in(d)} hs[s] + hs[d] ) + b,  hs = (A@W)*dinv[row]
// Pull/logits loops are 2-stage software-pipelined: indices (int4, aligned-down)
// prefetched 2 blocks ahead, row gathers issued 1 block ahead of consumption.
// ---------------------------------------------------------------------------

__global__ void cnt_k(const int* __restrict__ dst, int* __restrict__ cnt, int E) {
    int e = blockIdx.x * blockDim.x + threadIdx.x;
    if (e < E) atomicAdd(&cnt[dst[e]], 1);
}

__global__ void scan1_k(const int* __restrict__ cnt, int* __restrict__ incl,
                        int* __restrict__ bsum, int N) {
    __shared__ int sh[256];
    int i = blockIdx.x * 256 + threadIdx.x;
    int v = (i < N) ? cnt[i] : 0;
    sh[threadIdx.x] = v;
    __syncthreads();
#pragma unroll
    for (int off = 1; off < 256; off <<= 1) {
        int t = (threadIdx.x >= off) ? sh[threadIdx.x - off] : 0;
        __syncthreads();
        sh[threadIdx.x] += t;
        __syncthreads();
    }
    if (i < N) incl[i] = sh[threadIdx.x];
    if (threadIdx.x == 255) bsum[blockIdx.x] = sh[255];
}

__global__ void scan2_k(int* __restrict__ bsum, int NB) {
    __shared__ int sh[256];
    int v = (threadIdx.x < NB) ? bsum[threadIdx.x] : 0;
    sh[threadIdx.x] = v;
    __syncthreads();
#pragma unroll
    for (int off = 1; off < 256; off <<= 1) {
        int t = (threadIdx.x >= off) ? sh[threadIdx.x - off] : 0;
        __syncthreads();
        sh[threadIdx.x] += t;
        __syncthreads();
    }
    if (threadIdx.x < NB) bsum[threadIdx.x] = sh[threadIdx.x] - v;  // exclusive
}

__global__ void scan3_k(const int* __restrict__ cnt, const int* __restrict__ incl,
                        const int* __restrict__ bsum, int* __restrict__ rowptr,
                        int* __restrict__ cursor, float* __restrict__ dinv,
                        int N, int E) {
    int i = blockIdx.x * 256 + threadIdx.x;
    if (i < N) {
        int c = cnt[i];
        int excl = incl[i] - c + bsum[blockIdx.x];
        rowptr[i] = excl;
        cursor[i] = excl;
        dinv[i] = rsqrtf(1.0f + (float)c);
    }
    if (i == 0) rowptr[N] = E;
}

__global__ void fill_col_k(const int* __restrict__ src, const int* __restrict__ dst,
                           int* __restrict__ cursor, int* __restrict__ col,
                           int* __restrict__ eid, int E) {
    int e = blockIdx.x * blockDim.x + threadIdx.x;
    if (e < E) {
        int pos = atomicAdd(&cursor[dst[e]], 1);
        col[pos] = src[e];
        eid[pos] = e;
    }
}

// ---------------------------------------------------------------------------
// Tiled fp32 GEMM (k-major As): Out = (RELU? relu(A):A)[M,128] @ W[128,BN] * dscale[row]
// ---------------------------------------------------------------------------
template <int BN, bool RELU>
__global__ __launch_bounds__(256) void gemm_k128(const float* __restrict__ A,
                                                 const float* __restrict__ W,
                                                 const float* __restrict__ dscale,
                                                 float* __restrict__ Out, int M) {
    constexpr int K = 128, BM = 64, BK = 16;
    constexpr int TN = BN / 16;
    __shared__ float As[BK][BM + 4];
    __shared__ float Bs[BK][BN];

    const int tid = threadIdx.x;
    const int tx = tid & 15, ty = tid >> 4;
    const int row0 = blockIdx.x * BM;

    float acc[4][TN];
#pragma unroll
    for (int m = 0; m < 4; m++)
#pragma unroll
        for (int j = 0; j < TN; j++) acc[m][j] = 0.0f;

    const int ar = tid >> 2;
    const int ak = (tid & 3) * 4;

    for (int kt = 0; kt < K; kt += BK) {
        float4 av = make_float4(0.f, 0.f, 0.f, 0.f);
        int grow = row0 + ar;
        if (grow < M)
            av = *reinterpret_cast<const float4*>(A + (size_t)grow * K + kt + ak);
        if (RELU) {
            av.x = fmaxf(av.x, 0.f); av.y = fmaxf(av.y, 0.f);
            av.z = fmaxf(av.z, 0.f); av.w = fmaxf(av.w, 0.f);
        }
        As[ak + 0][ar] = av.x; As[ak + 1][ar] = av.y;
        As[ak + 2][ar] = av.z; As[ak + 3][ar] = av.w;

        constexpr int NB4 = BK * BN / 4;
#pragma unroll
        for (int b = 0; b < NB4 / 256; b++) {
            int f = b * 256 + tid;
            int brow = (f * 4) / BN;
            int bcol = (f * 4) % BN;
            float4 bv = *reinterpret_cast<const float4*>(W + (size_t)(kt + brow) * BN + bcol);
            *reinterpret_cast<float4*>(&Bs[brow][bcol]) = bv;
        }
        __syncthreads();

#pragma unroll
        for (int k = 0; k < BK; k++) {
            float4 a4 = *reinterpret_cast<const float4*>(&As[k][ty * 4]);
            float a[4] = {a4.x, a4.y, a4.z, a4.w};
            float bb[TN];
#pragma unroll
            for (int j4 = 0; j4 < TN / 4; j4++) {
                float4 b4 = *reinterpret_cast<const float4*>(&Bs[k][tx * TN + j4 * 4]);
                bb[j4 * 4 + 0] = b4.x; bb[j4 * 4 + 1] = b4.y;
                bb[j4 * 4 + 2] = b4.z; bb[j4 * 4 + 3] = b4.w;
            }
#pragma unroll
            for (int m = 0; m < 4; m++)
#pragma unroll
                for (int j = 0; j < TN; j++) acc[m][j] = fmaf(a[m], bb[j], acc[m][j]);
        }
        __syncthreads();
    }

#pragma unroll
    for (int m = 0; m < 4; m++) {
        int gr = row0 + ty * 4 + m;
        if (gr < M) {
            float dv = dscale[gr];
#pragma unroll
            for (int j4 = 0; j4 < TN / 4; j4++) {
                float4 o = make_float4(acc[m][j4 * 4 + 0] * dv, acc[m][j4 * 4 + 1] * dv,
                                       acc[m][j4 * 4 + 2] * dv, acc[m][j4 * 4 + 3] * dv);
                *reinterpret_cast<float4*>(Out + (size_t)gr * BN + tx * TN + j4 * 4) = o;
            }
        }
    }
}

#define ACC_PRED(g, pos)                                          \
    if ((pos) >= p0 && (pos) < p1) {                              \
        acc.x += (g).x; acc.y += (g).y;                           \
        acc.z += (g).z; acc.w += (g).w;                           \
    }

// ---------------------------------------------------------------------------
// pull128: one wave/node, 2 slots x 32 lanes (row = 32 float4), 8 edges/block,
// 2-stage pipeline: gathers of block i+1 + indices of block i+2 issued before
// consuming block i.
// ---------------------------------------------------------------------------
__global__ __launch_bounds__(256) void pull128_k(const int* __restrict__ rowptr,
                                                 const int* __restrict__ col,
                                                 const float4* __restrict__ hs4,
                                                 const float* __restrict__ dinv,
                                                 const float4* __restrict__ bias4,
                                                 float4* __restrict__ out4, int N) {
    int v = (int)((blockIdx.x * (size_t)blockDim.x + threadIdx.x) >> 6);
    if (v >= N) return;
    int lane = threadIdx.x & 63;
    int q = lane & 31, slot = lane >> 5;
    int p0 = rowptr[v], p1 = rowptr[v + 1];

    float4 acc = make_float4(0.f, 0.f, 0.f, 0.f);
    if (slot == 0) acc = hs4[(size_t)v * 32 + q];  // self row

    int astart = p0 & ~3;                   // 16B-align the int4 index loads
    int iters = (p1 - astart + 7) >> 3;     // blocks of 8 edges (2 slots x 4)
    const int* cp = col + astart + slot * 4;
    int base = astart + slot * 4;

    // prologue: block 0 indices+gathers, block 1 indices
    int4 cA = *reinterpret_cast<const int4*>(cp);
    float4 a0 = hs4[(size_t)cA.x * 32 + q];
    float4 a1 = hs4[(size_t)cA.y * 32 + q];
    float4 a2 = hs4[(size_t)cA.z * 32 + q];
    float4 a3 = hs4[(size_t)cA.w * 32 + q];
    int4 cB = *reinterpret_cast<const int4*>(cp + 8);

    for (int i = 0; i < iters; i++) {
        float4 b0, b1, b2, b3;
        if (i + 1 < iters) {                 // wave-uniform guard (no demand waste)
            b0 = hs4[(size_t)cB.x * 32 + q];
            b1 = hs4[(size_t)cB.y * 32 + q];
            b2 = hs4[(size_t)cB.z * 32 + q];
            b3 = hs4[(size_t)cB.w * 32 + q];
            cB = *reinterpret_cast<const int4*>(cp + 8 * (i + 2));
        }
        int pos = base + 8 * i;
        ACC_PRED(a0, pos + 0)
        ACC_PRED(a1, pos + 1)
        ACC_PRED(a2, pos + 2)
        ACC_PRED(a3, pos + 3)
        if (i + 1 < iters) { a0 = b0; a1 = b1; a2 = b2; a3 = b3; }
    }

    acc.x += __shfl_xor(acc.x, 32);
    acc.y += __shfl_xor(acc.y, 32);
    acc.z += __shfl_xor(acc.z, 32);
    acc.w += __shfl_xor(acc.w, 32);

    if (slot == 0) {
        float dv = dinv[v];
        float4 bv = bias4[q];
        out4[(size_t)v * 32 + q] = make_float4(fmaf(acc.x, dv, bv.x), fmaf(acc.y, dv, bv.y),
                                               fmaf(acc.z, dv, bv.z), fmaf(acc.w, dv, bv.w));
    }
}

// ---------------------------------------------------------------------------
// pull64: one wave/node, 4 slots x 16 lanes (row = 16 float4), 16 edges/block,
// same 2-stage pipeline.
// ---------------------------------------------------------------------------
__global__ __launch_bounds__(256) void pull64_k(const int* __restrict__ rowptr,
                                                const int* __restrict__ col,
                                                const float4* __restrict__ hs4,
                                                const float* __restrict__ dinv,
                                                const float4* __restrict__ bias4,
                                                float4* __restrict__ out4, int N) {
    int v = (int)((blockIdx.x * (size_t)blockDim.x + threadIdx.x) >> 6);
    if (v >= N) return;
    int lane = threadIdx.x & 63;
    int q = lane & 15, slot = lane >> 4;
    int p0 = rowptr[v], p1 = rowptr[v + 1];

    float4 acc = make_float4(0.f, 0.f, 0.f, 0.f);
    if (slot == 0) acc = hs4[(size_t)v * 16 + q];  // self row

    int astart = p0 & ~3;
    int iters = (p1 - astart + 15) >> 4;    // blocks of 16 edges (4 slots x 4)
    const int* cp = col + astart + slot * 4;
    int base = astart + slot * 4;

    int4 cA = *reinterpret_cast<const int4*>(cp);
    float4 a0 = hs4[(size_t)cA.x * 16 + q];
    float4 a1 = hs4[(size_t)cA.y * 16 + q];
    float4 a2 = hs4[(size_t)cA.z * 16 + q];
    float4 a3 = hs4[(size_t)cA.w * 16 + q];
    int4 cB = *reinterpret_cast<const int4*>(cp + 16);

    for (int i = 0; i < iters; i++) {
        float4 b0, b1, b2, b3;
        if (i + 1 < iters) {
            b0 = hs4[(size_t)cB.x * 16 + q];
            b1 = hs4[(size_t)cB.y * 16 + q];
            b2 = hs4[(size_t)cB.z * 16 + q];
            b3 = hs4[(size_t)cB.w * 16 + q];
            cB = *reinterpret_cast<const int4*>(cp + 16 * (i + 2));
        }
        int pos = base + 16 * i;
        ACC_PRED(a0, pos + 0)
        ACC_PRED(a1, pos + 1)
        ACC_PRED(a2, pos + 2)
        ACC_PRED(a3, pos + 3)
        if (i + 1 < iters) { a0 = b0; a1 = b1; a2 = b2; a3 = b3; }
    }

#pragma unroll
    for (int off = 16; off <= 32; off <<= 1) {
        acc.x += __shfl_xor(acc.x, off);
        acc.y += __shfl_xor(acc.y, off);
        acc.z += __shfl_xor(acc.z, off);
        acc.w += __shfl_xor(acc.w, off);
    }

    if (slot == 0) {
        float dv = dinv[v];
        float4 bv = bias4[q];
        out4[(size_t)v * 16 + q] = make_float4(fmaf(acc.x, dv, bv.x), fmaf(acc.y, dv, bv.y),
                                               fmaf(acc.z, dv, bv.z), fmaf(acc.w, dv, bv.w));
    }
}

// ---------------------------------------------------------------------------
// logits via CSR: one wave/dst node; dst row loaded once; src rows gathered with
// the same pipelined scheme (4 slots x 16 lanes, 16 edges/block). eid pipelined.
// ---------------------------------------------------------------------------
__global__ __launch_bounds__(256) void logits_csr_k(const int* __restrict__ rowptr,
                                                    const int* __restrict__ col,
                                                    const int* __restrict__ eid,
                                                    const float4* __restrict__ h4,
                                                    float* __restrict__ out, int N) {
    int v = (int)((blockIdx.x * (size_t)blockDim.x + threadIdx.x) >> 6);
    if (v >= N) return;
    int lane = threadIdx.x & 63;
    int q = lane & 15, slot = lane >> 4;
    int p0 = rowptr[v], p1 = rowptr[v + 1];
    if (p0 == p1) return;

    float4 rd = h4[(size_t)v * 16 + q];  // dst row (wave-resident)

    int astart = p0 & ~3;
    int iters = (p1 - astart + 15) >> 4;
    const int* cp = col + astart + slot * 4;
    const int* ep = eid + astart + slot * 4;
    int base = astart + slot * 4;

    int4 cA = *reinterpret_cast<const int4*>(cp);
    int4 eA = *reinterpret_cast<const int4*>(ep);
    float4 a0 = h4[(size_t)cA.x * 16 + q];
    float4 a1 = h4[(size_t)cA.y * 16 + q];
    float4 a2 = h4[(size_t)cA.z * 16 + q];
    float4 a3 = h4[(size_t)cA.w * 16 + q];
    int4 cB = *reinterpret_cast<const int4*>(cp + 16);
    int4 eB = *reinterpret_cast<const int4*>(ep + 16);

    for (int i = 0; i < iters; i++) {
        float4 b0, b1, b2, b3;
        if (i + 1 < iters) {
            b0 = h4[(size_t)cB.x * 16 + q];
            b1 = h4[(size_t)cB.y * 16 + q];
            b2 = h4[(size_t)cB.z * 16 + q];
            b3 = h4[(size_t)cB.w * 16 + q];
            cB = *reinterpret_cast<const int4*>(cp + 16 * (i + 2));
        }
        int pos = base + 16 * i;
        float t0 = rd.x * a0.x + rd.y * a0.y + rd.z * a0.z + rd.w * a0.w;
        float t1 = rd.x * a1.x + rd.y * a1.y + rd.z * a1.z + rd.w * a1.w;
        float t2 = rd.x * a2.x + rd.y * a2.y + rd.z * a2.z + rd.w * a2.w;
        float t3 = rd.x * a3.x + rd.y * a3.y + rd.z * a3.z + rd.w * a3.w;
#pragma unroll
        for (int off = 1; off < 16; off <<= 1) {
            t0 += __shfl_xor(t0, off);
            t1 += __shfl_xor(t1, off);
            t2 += __shfl_xor(t2, off);
            t3 += __shfl_xor(t3, off);
        }
        if (q == 0) {
            if (pos + 0 >= p0 && pos + 0 < p1) out[eA.x] = t0;
            if (pos + 1 >= p0 && pos + 1 < p1) out[eA.y] = t1;
            if (pos + 2 >= p0 && pos + 2 < p1) out[eA.z] = t2;
            if (pos + 3 >= p0 && pos + 3 < p1) out[eA.w] = t3;
        }
        if (i + 1 < iters) {
            a0 = b0; a1 = b1; a2 = b2; a3 = b3;
            eA = eB;
            eB = *reinterpret_cast<const int4*>(ep + 16 * (i + 2));
        }
    }
}

extern "C" void kernel_launch(void* const* d_in, const int* in_sizes, int n_in,
                              void* d_out, int out_size, void* d_ws, size_t ws_size,
                              hipStream_t stream) {
    const float* x  = (const float*)d_in[0];
    const int* ei   = (const int*)d_in[1];   // int32 (harness converts ints)
    const float* W1 = (const float*)d_in[2];
    const float* b1 = (const float*)d_in[3];
    const float* W2 = (const float*)d_in[4];
    const float* b2 = (const float*)d_in[5];
    float* out = (float*)d_out;

    const int N = in_sizes[0] / 128;   // 50000
    const int E = in_sizes[1] / 2;     // 800000
    const int* src = ei;
    const int* dst = ei + E;
    const int PAD = 64;                // col/eid overread pad (pipeline reads ahead)

    // ---- workspace ----
    // floats: dinv[50176] | bufA[N*128] | bufB[N*128]
    // ints:   cnt[N] | incl[N] | rowptr[N+1] | cursor[N] | bsum[256] | col[E+PAD] | eid[E+PAD]
    float* ws   = (float*)d_ws;
    float* dinv = ws;
    float* bufA = ws + 50176;
    float* bufB = bufA + (size_t)N * 128;
    float* hs1  = bufA;
    float* agg1 = bufB;
    float* g2s  = bufA;
    float* agg2 = bufA + (size_t)N * 64;

    int* ibase  = (int*)(bufB + (size_t)N * 128);
    int* cnt    = ibase;
    int* incl   = cnt + N;
    int* rowptr = incl + N;
    int* cursor = rowptr + (N + 1);
    int* bsum   = cursor + N;
    int* col    = bsum + 256;
    int* eid    = col + E + PAD;

    const int B = 256;
    const int NB = (N + 255) / 256;
    const unsigned nodeBlocks = (unsigned)(((size_t)N * 64 + 255) / 256);

    // ---- CSR build + dinv ----
    hipMemsetAsync(cnt, 0, (size_t)N * sizeof(int), stream);
    hipMemsetAsync(col + E, 0, PAD * sizeof(int), stream);   // zero pad: safe garbage gathers (row 0)
    hipMemsetAsync(eid + E, 0, PAD * sizeof(int), stream);
    cnt_k<<<(E + B - 1) / B, B, 0, stream>>>(dst, cnt, E);
    scan1_k<<<NB, 256, 0, stream>>>(cnt, incl, bsum, N);
    scan2_k<<<1, 256, 0, stream>>>(bsum, NB);
    scan3_k<<<NB, 256, 0, stream>>>(cnt, incl, bsum, rowptr, cursor, dinv, N, E);
    fill_col_k<<<(E + B - 1) / B, B, 0, stream>>>(src, dst, cursor, col, eid, E);

    // ---- layer 1 ----
    gemm_k128<128, false><<<(N + 63) / 64, 256, 0, stream>>>(x, W1, dinv, hs1, N);
    pull128_k<<<nodeBlocks, 256, 0, stream>>>(rowptr, col, (const float4*)hs1, dinv,
                                              (const float4*)b1, (float4*)agg1, N);

    // ---- layer 2 ----
    gemm_k128<64, true><<<(N + 63) / 64, 256, 0, stream>>>(agg1, W2, dinv, g2s, N);
    pull64_k<<<nodeBlocks, 256, 0, stream>>>(rowptr, col, (const float4*)g2s, dinv,
                                             (const float4*)b2, (float4*)agg2, N);

    // ---- edge logits (CSR order, dst row amortized) ----
    logits_csr_k<<<nodeBlocks, 256, 0, stream>>>(rowptr, col, eid, (const float4*)agg2, out, N);
}

// Round 7
// 282.616 us; speedup vs baseline: 1.0457x; 1.0457x over previous
//
#include <hip/hip_runtime.h>
#include <hip/hip_bf16.h>

// ---------------------------------------------------------------------------
// GCN 2-layer + edge dot logits, CSR-pull aggregation.
// agg[d] = dinv[d] * ( sum_{s in in(d)} hs[s] + hs[d] ) + b,  hs = (A@W)*dinv[row]
// Round 7: round-5 pull/logits (best known; gathers are at the ~3.7 TB/s
// L3-fill roofline) + high-efficiency BM=128 GEMM (8x8 micro-tile).
// ---------------------------------------------------------------------------

__global__ void cnt_k(const int* __restrict__ dst, int* __restrict__ cnt, int E) {
    int t = blockIdx.x * blockDim.x + threadIdx.x;
    int e = t * 4;
    if (e + 4 <= E) {
        int4 d4 = *reinterpret_cast<const int4*>(dst + e);
        atomicAdd(&cnt[d4.x], 1);
        atomicAdd(&cnt[d4.y], 1);
        atomicAdd(&cnt[d4.z], 1);
        atomicAdd(&cnt[d4.w], 1);
    } else {
        for (int i = e; i < E; i++) atomicAdd(&cnt[dst[i]], 1);
    }
}

__global__ void scan1_k(const int* __restrict__ cnt, int* __restrict__ incl,
                        int* __restrict__ bsum, int N) {
    __shared__ int sh[256];
    int i = blockIdx.x * 256 + threadIdx.x;
    int v = (i < N) ? cnt[i] : 0;
    sh[threadIdx.x] = v;
    __syncthreads();
#pragma unroll
    for (int off = 1; off < 256; off <<= 1) {
        int t = (threadIdx.x >= off) ? sh[threadIdx.x - off] : 0;
        __syncthreads();
        sh[threadIdx.x] += t;
        __syncthreads();
    }
    if (i < N) incl[i] = sh[threadIdx.x];
    if (threadIdx.x == 255) bsum[blockIdx.x] = sh[255];
}

__global__ void scan2_k(int* __restrict__ bsum, int NB) {
    __shared__ int sh[256];
    int v = (threadIdx.x < NB) ? bsum[threadIdx.x] : 0;
    sh[threadIdx.x] = v;
    __syncthreads();
#pragma unroll
    for (int off = 1; off < 256; off <<= 1) {
        int t = (threadIdx.x >= off) ? sh[threadIdx.x - off] : 0;
        __syncthreads();
        sh[threadIdx.x] += t;
        __syncthreads();
    }
    if (threadIdx.x < NB) bsum[threadIdx.x] = sh[threadIdx.x] - v;  // exclusive
}

__global__ void scan3_k(const int* __restrict__ cnt, const int* __restrict__ incl,
                        const int* __restrict__ bsum, int* __restrict__ rowptr,
                        int* __restrict__ cursor, float* __restrict__ dinv,
                        int N, int E) {
    int i = blockIdx.x * 256 + threadIdx.x;
    if (i < N) {
        int c = cnt[i];
        int excl = incl[i] - c + bsum[blockIdx.x];
        rowptr[i] = excl;
        cursor[i] = excl;
        dinv[i] = rsqrtf(1.0f + (float)c);
    }
    if (i == 0) rowptr[N] = E;
}

__global__ void fill_col_k(const int* __restrict__ src, const int* __restrict__ dst,
                           int* __restrict__ cursor, int* __restrict__ col,
                           int* __restrict__ eid, int E) {
    int e = blockIdx.x * blockDim.x + threadIdx.x;
    if (e < E) {
        int pos = atomicAdd(&cursor[dst[e]], 1);
        col[pos] = src[e];
        eid[pos] = e;
    }
}

// ---------------------------------------------------------------------------
// GEMM: Out[M,BN] = (RELU? relu(A):A)[M,128] @ W[128,BN] * dscale[row]
// BM=128, BK=16, 256 threads (16x16), micro-tile 8 x (BN/16).
// k-major As with pad 4 (2-way write alias = free); all LDS I/O is float4.
// Per thread-k: 2 b128 A + TN/4 b128 B + 8*TN FMA.
// ---------------------------------------------------------------------------
template <int BN, bool RELU>
__global__ __launch_bounds__(256) void gemm_big(const float* __restrict__ A,
                                                const float* __restrict__ W,
                                                const float* __restrict__ dscale,
                                                float* __restrict__ Out, int M) {
    constexpr int K = 128, BM = 128, BK = 16;
    constexpr int TM = 8;
    constexpr int TN = BN / 16;           // 8 (BN=128) or 4 (BN=64)
    __shared__ float As[BK][BM + 4];      // k-major
    __shared__ float Bs[BK][BN + 4];

    const int tid = threadIdx.x;
    const int tx = tid & 15;              // col group: cols tx*TN .. tx*TN+TN-1
    const int ty = tid >> 4;              // row group: rows ty*8 .. ty*8+7
    const int row0 = blockIdx.x * BM;

    float acc[TM][TN];
#pragma unroll
    for (int m = 0; m < TM; m++)
#pragma unroll
        for (int n = 0; n < TN; n++) acc[m][n] = 0.0f;

    for (int kt = 0; kt < K; kt += BK) {
        // --- stage A (128x16, k-major): 2 float4 per thread ---
#pragma unroll
        for (int s = 0; s < (BM * BK) / (256 * 4); s++) {
            int flat = tid + s * 256;
            int row = flat >> 2;            // 0..127
            int kq = (flat & 3) * 4;        // 0,4,8,12
            float4 av = make_float4(0.f, 0.f, 0.f, 0.f);
            int gr = row0 + row;
            if (gr < M)
                av = *reinterpret_cast<const float4*>(A + (size_t)gr * K + kt + kq);
            if (RELU) {
                av.x = fmaxf(av.x, 0.f); av.y = fmaxf(av.y, 0.f);
                av.z = fmaxf(av.z, 0.f); av.w = fmaxf(av.w, 0.f);
            }
            As[kq + 0][row] = av.x; As[kq + 1][row] = av.y;
            As[kq + 2][row] = av.z; As[kq + 3][row] = av.w;
        }
        // --- stage B (16xBN): BK*BN/1024 float4 per thread ---
#pragma unroll
        for (int s = 0; s < (BK * BN) / (256 * 4); s++) {
            int flat = tid + s * 256;
            int r = flat / (BN / 4);
            int c4 = (flat % (BN / 4)) * 4;
            float4 bv = *reinterpret_cast<const float4*>(W + (size_t)(kt + r) * BN + c4);
            *reinterpret_cast<float4*>(&Bs[r][c4]) = bv;
        }
        __syncthreads();

#pragma unroll
        for (int k = 0; k < BK; k++) {
            float a[TM], b[TN];
            *reinterpret_cast<float4*>(&a[0]) = *reinterpret_cast<const float4*>(&As[k][ty * TM + 0]);
            *reinterpret_cast<float4*>(&a[4]) = *reinterpret_cast<const float4*>(&As[k][ty * TM + 4]);
            *reinterpret_cast<float4*>(&b[0]) = *reinterpret_cast<const float4*>(&Bs[k][tx * TN + 0]);
            if (TN == 8)
                *reinterpret_cast<float4*>(&b[4]) = *reinterpret_cast<const float4*>(&Bs[k][tx * TN + 4]);
#pragma unroll
            for (int m = 0; m < TM; m++)
#pragma unroll
                for (int n = 0; n < TN; n++) acc[m][n] = fmaf(a[m], b[n], acc[m][n]);
        }
        __syncthreads();
    }

#pragma unroll
    for (int m = 0; m < TM; m++) {
        int gr = row0 + ty * TM + m;
        if (gr < M) {
            float dv = dscale[gr];
#pragma unroll
            for (int n4 = 0; n4 < TN / 4; n4++) {
                float4 o = make_float4(acc[m][n4 * 4 + 0] * dv, acc[m][n4 * 4 + 1] * dv,
                                       acc[m][n4 * 4 + 2] * dv, acc[m][n4 * 4 + 3] * dv);
                *reinterpret_cast<float4*>(Out + (size_t)gr * BN + tx * TN + n4 * 4) = o;
            }
        }
    }
}

// ---------------------------------------------------------------------------
// pull128 (round-5): one wave/node, 2 slots x 32 lanes (row = 32 float4).
// ---------------------------------------------------------------------------
__global__ __launch_bounds__(256) void pull128_k(const int* __restrict__ rowptr,
                                                 const int* __restrict__ col,
                                                 const float4* __restrict__ hs4,
                                                 const float* __restrict__ dinv,
                                                 const float4* __restrict__ bias4,
                                                 float4* __restrict__ out4, int N) {
    int v = (int)((blockIdx.x * (size_t)blockDim.x + threadIdx.x) >> 6);
    if (v >= N) return;
    int lane = threadIdx.x & 63;
    int q = lane & 31, slot = lane >> 5;
    int p0 = rowptr[v], p1 = rowptr[v + 1];

    float4 acc = make_float4(0.f, 0.f, 0.f, 0.f);
    if (slot == 0) acc = hs4[(size_t)v * 32 + q];  // self row

    int p = p0;
    for (; p + 8 <= p1; p += 8) {
        int ia = col[p + slot], ib = col[p + 2 + slot];
        int ic = col[p + 4 + slot], id = col[p + 6 + slot];
        float4 a = hs4[(size_t)ia * 32 + q];
        float4 b = hs4[(size_t)ib * 32 + q];
        float4 c = hs4[(size_t)ic * 32 + q];
        float4 d = hs4[(size_t)id * 32 + q];
        acc.x += (a.x + b.x) + (c.x + d.x);
        acc.y += (a.y + b.y) + (c.y + d.y);
        acc.z += (a.z + b.z) + (c.z + d.z);
        acc.w += (a.w + b.w) + (c.w + d.w);
    }
    for (; p + 2 <= p1; p += 2) {
        int ia = col[p + slot];
        float4 a = hs4[(size_t)ia * 32 + q];
        acc.x += a.x; acc.y += a.y; acc.z += a.z; acc.w += a.w;
    }
    if (p < p1 && slot == 0) {
        float4 a = hs4[(size_t)col[p] * 32 + q];
        acc.x += a.x; acc.y += a.y; acc.z += a.z; acc.w += a.w;
    }

    acc.x += __shfl_xor(acc.x, 32);
    acc.y += __shfl_xor(acc.y, 32);
    acc.z += __shfl_xor(acc.z, 32);
    acc.w += __shfl_xor(acc.w, 32);

    if (slot == 0) {
        float dv = dinv[v];
        float4 bv = bias4[q];
        out4[(size_t)v * 32 + q] = make_float4(fmaf(acc.x, dv, bv.x), fmaf(acc.y, dv, bv.y),
                                               fmaf(acc.z, dv, bv.z), fmaf(acc.w, dv, bv.w));
    }
}

// ---------------------------------------------------------------------------
// pull64 (round-5): one wave/node, 4 slots x 16 lanes (row = 16 float4).
// ---------------------------------------------------------------------------
__global__ __launch_bounds__(256) void pull64_k(const int* __restrict__ rowptr,
                                                const int* __restrict__ col,
                                                const float4* __restrict__ hs4,
                                                const float* __restrict__ dinv,
                                                const float4* __restrict__ bias4,
                                                float4* __restrict__ out4, int N) {
    int v = (int)((blockIdx.x * (size_t)blockDim.x + threadIdx.x) >> 6);
    if (v >= N) return;
    int lane = threadIdx.x & 63;
    int q = lane & 15, slot = lane >> 4;
    int p0 = rowptr[v], p1 = rowptr[v + 1];

    float4 acc = make_float4(0.f, 0.f, 0.f, 0.f);
    if (slot == 0) acc = hs4[(size_t)v * 16 + q];  // self row

    int p = p0;
    for (; p + 8 <= p1; p += 8) {
        int ia = col[p + slot], ib = col[p + 4 + slot];
        float4 a = hs4[(size_t)ia * 16 + q];
        float4 b = hs4[(size_t)ib * 16 + q];
        acc.x += a.x + b.x; acc.y += a.y + b.y;
        acc.z += a.z + b.z; acc.w += a.w + b.w;
    }
    for (; p + 4 <= p1; p += 4) {
        float4 a = hs4[(size_t)col[p + slot] * 16 + q];
        acc.x += a.x; acc.y += a.y; acc.z += a.z; acc.w += a.w;
    }
    int rem = p1 - p;  // 0..3
    if (slot < rem) {
        float4 a = hs4[(size_t)col[p + slot] * 16 + q];
        acc.x += a.x; acc.y += a.y; acc.z += a.z; acc.w += a.w;
    }

#pragma unroll
    for (int off = 16; off <= 32; off <<= 1) {
        acc.x += __shfl_xor(acc.x, off);
        acc.y += __shfl_xor(acc.y, off);
        acc.z += __shfl_xor(acc.z, off);
        acc.w += __shfl_xor(acc.w, off);
    }

    if (slot == 0) {
        float dv = dinv[v];
        float4 bv = bias4[q];
        out4[(size_t)v * 16 + q] = make_float4(fmaf(acc.x, dv, bv.x), fmaf(acc.y, dv, bv.y),
                                               fmaf(acc.z, dv, bv.z), fmaf(acc.w, dv, bv.w));
    }
}

// ---------------------------------------------------------------------------
// logits (round-5, CSR): one wave/dst node; dst row loaded once; src gathered.
// ---------------------------------------------------------------------------
__global__ __launch_bounds__(256) void logits_csr_k(const int* __restrict__ rowptr,
                                                    const int* __restrict__ col,
                                                    const int* __restrict__ eid,
                                                    const float4* __restrict__ h4,
                                                    float* __restrict__ out, int N) {
    int v = (int)((blockIdx.x * (size_t)blockDim.x + threadIdx.x) >> 6);
    if (v >= N) return;
    int lane = threadIdx.x & 63;
    int q = lane & 15, slot = lane >> 4;
    int p0 = rowptr[v], p1 = rowptr[v + 1];
    if (p0 == p1) return;

    float4 rd = h4[(size_t)v * 16 + q];  // dst row (wave-resident)

    int p = p0;
    for (; p + 8 <= p1; p += 8) {
        int s0 = col[p + slot], s1 = col[p + 4 + slot];
        int e0 = eid[p + slot], e1 = eid[p + 4 + slot];
        float4 ra = h4[(size_t)s0 * 16 + q];
        float4 rb = h4[(size_t)s1 * 16 + q];
        float t0 = rd.x * ra.x + rd.y * ra.y + rd.z * ra.z + rd.w * ra.w;
        float t1 = rd.x * rb.x + rd.y * rb.y + rd.z * rb.z + rd.w * rb.w;
#pragma unroll
        for (int off = 1; off < 16; off <<= 1) {
            t0 += __shfl_xor(t0, off);
            t1 += __shfl_xor(t1, off);
        }
        if (q == 0) { out[e0] = t0; out[e1] = t1; }
    }
    for (; p + 4 <= p1; p += 4) {
        int s0 = col[p + slot];
        int e0 = eid[p + slot];
        float4 ra = h4[(size_t)s0 * 16 + q];
        float t0 = rd.x * ra.x + rd.y * ra.y + rd.z * ra.z + rd.w * ra.w;
#pragma unroll
        for (int off = 1; off < 16; off <<= 1) t0 += __shfl_xor(t0, off);
        if (q == 0) out[e0] = t0;
    }
    int rem = p1 - p;  // 0..3
    if (slot < rem) {
        int s0 = col[p + slot];
        int e0 = eid[p + slot];
        float4 ra = h4[(size_t)s0 * 16 + q];
        float t0 = rd.x * ra.x + rd.y * ra.y + rd.z * ra.z + rd.w * ra.w;
#pragma unroll
        for (int off = 1; off < 16; off <<= 1) t0 += __shfl_xor(t0, off);
        if (q == 0) out[e0] = t0;
    }
}

extern "C" void kernel_launch(void* const* d_in, const int* in_sizes, int n_in,
                              void* d_out, int out_size, void* d_ws, size_t ws_size,
                              hipStream_t stream) {
    const float* x  = (const float*)d_in[0];
    const int* ei   = (const int*)d_in[1];   // int32 (harness converts ints)
    const float* W1 = (const float*)d_in[2];
    const float* b1 = (const float*)d_in[3];
    const float* W2 = (const float*)d_in[4];
    const float* b2 = (const float*)d_in[5];
    float* out = (float*)d_out;

    const int N = in_sizes[0] / 128;   // 50000
    const int E = in_sizes[1] / 2;     // 800000
    const int* src = ei;
    const int* dst = ei + E;

    // ---- workspace ----
    // floats: dinv[50176] | bufA[N*128] | bufB[N*128]
    // ints:   cnt[N] | incl[N] | rowptr[N+1] | cursor[N] | bsum[256] | col[E] | eid[E]
    float* ws   = (float*)d_ws;
    float* dinv = ws;
    float* bufA = ws + 50176;
    float* bufB = bufA + (size_t)N * 128;
    float* hs1  = bufA;
    float* agg1 = bufB;
    float* g2s  = bufA;
    float* agg2 = bufA + (size_t)N * 64;

    int* ibase  = (int*)(bufB + (size_t)N * 128);
    int* cnt    = ibase;
    int* incl   = cnt + N;
    int* rowptr = incl + N;
    int* cursor = rowptr + (N + 1);
    int* bsum   = cursor + N;
    int* col    = bsum + 256;
    int* eid    = col + E;

    const int B = 256;
    const int NB = (N + 255) / 256;
    const unsigned nodeBlocks = (unsigned)(((size_t)N * 64 + 255) / 256);

    // ---- CSR build + dinv ----
    hipMemsetAsync(cnt, 0, (size_t)N * sizeof(int), stream);
    cnt_k<<<(E / 4 + B - 1) / B, B, 0, stream>>>(dst, cnt, E);
    scan1_k<<<NB, 256, 0, stream>>>(cnt, incl, bsum, N);
    scan2_k<<<1, 256, 0, stream>>>(bsum, NB);
    scan3_k<<<NB, 256, 0, stream>>>(cnt, incl, bsum, rowptr, cursor, dinv, N, E);
    fill_col_k<<<(E + B - 1) / B, B, 0, stream>>>(src, dst, cursor, col, eid, E);

    // ---- layer 1: hs1 = (x@W1)*dinv ; agg1 = pull + b1 ----
    gemm_big<128, false><<<(N + 127) / 128, 256, 0, stream>>>(x, W1, dinv, hs1, N);
    pull128_k<<<nodeBlocks, 256, 0, stream>>>(rowptr, col, (const float4*)hs1, dinv,
                                              (const float4*)b1, (float4*)agg1, N);

    // ---- layer 2: g2s = (relu(agg1)@W2)*dinv ; agg2 = pull + b2 ----
    gemm_big<64, true><<<(N + 127) / 128, 256, 0, stream>>>(agg1, W2, dinv, g2s, N);
    pull64_k<<<nodeBlocks, 256, 0, stream>>>(rowptr, col, (const float4*)g2s, dinv,
                                             (const float4*)b2, (float4*)agg2, N);

    // ---- edge logits (CSR order, dst row amortized) ----
    logits_csr_k<<<nodeBlocks, 256, 0, stream>>>(rowptr, col, eid, (const float4*)agg2, out, N);
}

// Round 8
// 277.954 us; speedup vs baseline: 1.0633x; 1.0168x over previous
//
#include <hip/hip_runtime.h>
#include <hip/hip_bf16.h>

// ---------------------------------------------------------------------------
// GCN 2-layer + edge dot logits, CSR-pull aggregation.
// agg[d] = dinv[d] * ( sum_{s in in(d)} hs[s] + hs[d] ) + b,  hs = (A@W)*dinv[row]
// Round 8: round-5 GEMM/pulls (best known; gathers at ~3.7 TB/s fill ceiling),
// packed int2 {src,eid} CSR payload (halves scattered fill writes), fused scan.
// ---------------------------------------------------------------------------

__global__ void cnt_k(const int* __restrict__ dst, int* __restrict__ cnt, int E) {
    int t = blockIdx.x * blockDim.x + threadIdx.x;
    int e = t * 4;
    if (e + 4 <= E) {
        int4 d4 = *reinterpret_cast<const int4*>(dst + e);
        atomicAdd(&cnt[d4.x], 1);
        atomicAdd(&cnt[d4.y], 1);
        atomicAdd(&cnt[d4.z], 1);
        atomicAdd(&cnt[d4.w], 1);
    } else {
        for (int i = e; i < E; i++) atomicAdd(&cnt[dst[i]], 1);
    }
}

__global__ void scan1_k(const int* __restrict__ cnt, int* __restrict__ incl,
                        int* __restrict__ bsum, int N) {
    __shared__ int sh[256];
    int i = blockIdx.x * 256 + threadIdx.x;
    int v = (i < N) ? cnt[i] : 0;
    sh[threadIdx.x] = v;
    __syncthreads();
#pragma unroll
    for (int off = 1; off < 256; off <<= 1) {
        int t = (threadIdx.x >= off) ? sh[threadIdx.x - off] : 0;
        __syncthreads();
        sh[threadIdx.x] += t;
        __syncthreads();
    }
    if (i < N) incl[i] = sh[threadIdx.x];
    if (threadIdx.x == 255) bsum[blockIdx.x] = sh[255];
}

// fused scan2+scan3: every block scans bsum redundantly in LDS (NB<=256),
// picks its own exclusive offset, then does the elementwise writeback.
__global__ __launch_bounds__(256) void scan23_k(const int* __restrict__ cnt,
                                                const int* __restrict__ incl,
                                                const int* __restrict__ bsum,
                                                int* __restrict__ rowptr,
                                                int* __restrict__ cursor,
                                                float* __restrict__ dinv,
                                                int N, int E, int NB) {
    __shared__ int sh[256];
    __shared__ int blockOff;
    int v = (threadIdx.x < NB) ? bsum[threadIdx.x] : 0;
    sh[threadIdx.x] = v;
    __syncthreads();
#pragma unroll
    for (int off = 1; off < 256; off <<= 1) {
        int t = (threadIdx.x >= off) ? sh[threadIdx.x - off] : 0;
        __syncthreads();
        sh[threadIdx.x] += t;
        __syncthreads();
    }
    if (threadIdx.x == blockIdx.x) blockOff = sh[threadIdx.x] - v;  // exclusive
    __syncthreads();
    int i = blockIdx.x * 256 + threadIdx.x;
    if (i < N) {
        int c = cnt[i];
        int excl = incl[i] - c + blockOff;
        rowptr[i] = excl;
        cursor[i] = excl;
        dinv[i] = rsqrtf(1.0f + (float)c);  // +1 self-loop
    }
    if (i == 0) rowptr[N] = E;
}

// packed payload: one scattered 8B store instead of two scattered 4B stores
__global__ void fill_col2_k(const int* __restrict__ src, const int* __restrict__ dst,
                            int* __restrict__ cursor, int2* __restrict__ col2, int E) {
    int e = blockIdx.x * blockDim.x + threadIdx.x;
    if (e < E) {
        int pos = atomicAdd(&cursor[dst[e]], 1);
        col2[pos] = make_int2(src[e], e);
    }
}

// ---------------------------------------------------------------------------
// Tiled fp32 GEMM (round-5, k-major As): Out = (RELU? relu(A):A)[M,128] @ W[128,BN]
// * dscale[row].  BM=64, BK=16, 256 threads, micro-tile 4 x (BN/16).
// ---------------------------------------------------------------------------
template <int BN, bool RELU>
__global__ __launch_bounds__(256) void gemm_k128(const float* __restrict__ A,
                                                 const float* __restrict__ W,
                                                 const float* __restrict__ dscale,
                                                 float* __restrict__ Out, int M) {
    constexpr int K = 128, BM = 64, BK = 16;
    constexpr int TN = BN / 16;
    __shared__ float As[BK][BM + 4];
    __shared__ float Bs[BK][BN];

    const int tid = threadIdx.x;
    const int tx = tid & 15, ty = tid >> 4;
    const int row0 = blockIdx.x * BM;

    float acc[4][TN];
#pragma unroll
    for (int m = 0; m < 4; m++)
#pragma unroll
        for (int j = 0; j < TN; j++) acc[m][j] = 0.0f;

    const int ar = tid >> 2;
    const int ak = (tid & 3) * 4;

    for (int kt = 0; kt < K; kt += BK) {
        float4 av = make_float4(0.f, 0.f, 0.f, 0.f);
        int grow = row0 + ar;
        if (grow < M)
            av = *reinterpret_cast<const float4*>(A + (size_t)grow * K + kt + ak);
        if (RELU) {
            av.x = fmaxf(av.x, 0.f); av.y = fmaxf(av.y, 0.f);
            av.z = fmaxf(av.z, 0.f); av.w = fmaxf(av.w, 0.f);
        }
        As[ak + 0][ar] = av.x; As[ak + 1][ar] = av.y;
        As[ak + 2][ar] = av.z; As[ak + 3][ar] = av.w;

        constexpr int NB4 = BK * BN / 4;
#pragma unroll
        for (int b = 0; b < NB4 / 256; b++) {
            int f = b * 256 + tid;
            int brow = (f * 4) / BN;
            int bcol = (f * 4) % BN;
            float4 bv = *reinterpret_cast<const float4*>(W + (size_t)(kt + brow) * BN + bcol);
            *reinterpret_cast<float4*>(&Bs[brow][bcol]) = bv;
        }
        __syncthreads();

#pragma unroll
        for (int k = 0; k < BK; k++) {
            float4 a4 = *reinterpret_cast<const float4*>(&As[k][ty * 4]);
            float a[4] = {a4.x, a4.y, a4.z, a4.w};
            float bb[TN];
#pragma unroll
            for (int j4 = 0; j4 < TN / 4; j4++) {
                float4 b4 = *reinterpret_cast<const float4*>(&Bs[k][tx * TN + j4 * 4]);
                bb[j4 * 4 + 0] = b4.x; bb[j4 * 4 + 1] = b4.y;
                bb[j4 * 4 + 2] = b4.z; bb[j4 * 4 + 3] = b4.w;
            }
#pragma unroll
            for (int m = 0; m < 4; m++)
#pragma unroll
                for (int j = 0; j < TN; j++) acc[m][j] = fmaf(a[m], bb[j], acc[m][j]);
        }
        __syncthreads();
    }

#pragma unroll
    for (int m = 0; m < 4; m++) {
        int gr = row0 + ty * 4 + m;
        if (gr < M) {
            float dv = dscale[gr];
#pragma unroll
            for (int j4 = 0; j4 < TN / 4; j4++) {
                float4 o = make_float4(acc[m][j4 * 4 + 0] * dv, acc[m][j4 * 4 + 1] * dv,
                                       acc[m][j4 * 4 + 2] * dv, acc[m][j4 * 4 + 3] * dv);
                *reinterpret_cast<float4*>(Out + (size_t)gr * BN + tx * TN + j4 * 4) = o;
            }
        }
    }
}

// ---------------------------------------------------------------------------
// pull128: one wave/node, 2 slots x 32 lanes (row = 32 float4).
// ---------------------------------------------------------------------------
__global__ __launch_bounds__(256) void pull128_k(const int* __restrict__ rowptr,
                                                 const int2* __restrict__ col2,
                                                 const float4* __restrict__ hs4,
                                                 const float* __restrict__ dinv,
                                                 const float4* __restrict__ bias4,
                                                 float4* __restrict__ out4, int N) {
    int v = (int)((blockIdx.x * (size_t)blockDim.x + threadIdx.x) >> 6);
    if (v >= N) return;
    int lane = threadIdx.x & 63;
    int q = lane & 31, slot = lane >> 5;
    int p0 = rowptr[v], p1 = rowptr[v + 1];

    float4 acc = make_float4(0.f, 0.f, 0.f, 0.f);
    if (slot == 0) acc = hs4[(size_t)v * 32 + q];  // self row

    int p = p0;
    for (; p + 8 <= p1; p += 8) {
        int ia = col2[p + slot].x, ib = col2[p + 2 + slot].x;
        int ic = col2[p + 4 + slot].x, id = col2[p + 6 + slot].x;
        float4 a = hs4[(size_t)ia * 32 + q];
        float4 b = hs4[(size_t)ib * 32 + q];
        float4 c = hs4[(size_t)ic * 32 + q];
        float4 d = hs4[(size_t)id * 32 + q];
        acc.x += (a.x + b.x) + (c.x + d.x);
        acc.y += (a.y + b.y) + (c.y + d.y);
        acc.z += (a.z + b.z) + (c.z + d.z);
        acc.w += (a.w + b.w) + (c.w + d.w);
    }
    for (; p + 2 <= p1; p += 2) {
        int ia = col2[p + slot].x;
        float4 a = hs4[(size_t)ia * 32 + q];
        acc.x += a.x; acc.y += a.y; acc.z += a.z; acc.w += a.w;
    }
    if (p < p1 && slot == 0) {
        float4 a = hs4[(size_t)col2[p].x * 32 + q];
        acc.x += a.x; acc.y += a.y; acc.z += a.z; acc.w += a.w;
    }

    acc.x += __shfl_xor(acc.x, 32);
    acc.y += __shfl_xor(acc.y, 32);
    acc.z += __shfl_xor(acc.z, 32);
    acc.w += __shfl_xor(acc.w, 32);

    if (slot == 0) {
        float dv = dinv[v];
        float4 bv = bias4[q];
        out4[(size_t)v * 32 + q] = make_float4(fmaf(acc.x, dv, bv.x), fmaf(acc.y, dv, bv.y),
                                               fmaf(acc.z, dv, bv.z), fmaf(acc.w, dv, bv.w));
    }
}

// ---------------------------------------------------------------------------
// pull64: one wave/node, 4 slots x 16 lanes (row = 16 float4).
// ---------------------------------------------------------------------------
__global__ __launch_bounds__(256) void pull64_k(const int* __restrict__ rowptr,
                                                const int2* __restrict__ col2,
                                                const float4* __restrict__ hs4,
                                                const float* __restrict__ dinv,
                                                const float4* __restrict__ bias4,
                                                float4* __restrict__ out4, int N) {
    int v = (int)((blockIdx.x * (size_t)blockDim.x + threadIdx.x) >> 6);
    if (v >= N) return;
    int lane = threadIdx.x & 63;
    int q = lane & 15, slot = lane >> 4;
    int p0 = rowptr[v], p1 = rowptr[v + 1];

    float4 acc = make_float4(0.f, 0.f, 0.f, 0.f);
    if (slot == 0) acc = hs4[(size_t)v * 16 + q];  // self row

    int p = p0;
    for (; p + 8 <= p1; p += 8) {
        int ia = col2[p + slot].x, ib = col2[p + 4 + slot].x;
        float4 a = hs4[(size_t)ia * 16 + q];
        float4 b = hs4[(size_t)ib * 16 + q];
        acc.x += a.x + b.x; acc.y += a.y + b.y;
        acc.z += a.z + b.z; acc.w += a.w + b.w;
    }
    for (; p + 4 <= p1; p += 4) {
        float4 a = hs4[(size_t)col2[p + slot].x * 16 + q];
        acc.x += a.x; acc.y += a.y; acc.z += a.z; acc.w += a.w;
    }
    int rem = p1 - p;  // 0..3
    if (slot < rem) {
        float4 a = hs4[(size_t)col2[p + slot].x * 16 + q];
        acc.x += a.x; acc.y += a.y; acc.z += a.z; acc.w += a.w;
    }

#pragma unroll
    for (int off = 16; off <= 32; off <<= 1) {
        acc.x += __shfl_xor(acc.x, off);
        acc.y += __shfl_xor(acc.y, off);
        acc.z += __shfl_xor(acc.z, off);
        acc.w += __shfl_xor(acc.w, off);
    }

    if (slot == 0) {
        float dv = dinv[v];
        float4 bv = bias4[q];
        out4[(size_t)v * 16 + q] = make_float4(fmaf(acc.x, dv, bv.x), fmaf(acc.y, dv, bv.y),
                                               fmaf(acc.z, dv, bv.z), fmaf(acc.w, dv, bv.w));
    }
}

// ---------------------------------------------------------------------------
// logits via CSR: one wave/dst node; dst row loaded once; src rows gathered.
// col2 gives {src,eid} in one 8B load.
// ---------------------------------------------------------------------------
__global__ __launch_bounds__(256) void logits_csr_k(const int* __restrict__ rowptr,
                                                    const int2* __restrict__ col2,
                                                    const float4* __restrict__ h4,
                                                    float* __restrict__ out, int N) {
    int v = (int)((blockIdx.x * (size_t)blockDim.x + threadIdx.x) >> 6);
    if (v >= N) return;
    int lane = threadIdx.x & 63;
    int q = lane & 15, slot = lane >> 4;
    int p0 = rowptr[v], p1 = rowptr[v + 1];
    if (p0 == p1) return;

    float4 rd = h4[(size_t)v * 16 + q];  // dst row (wave-resident)

    int p = p0;
    for (; p + 8 <= p1; p += 8) {
        int2 ca = col2[p + slot], cb = col2[p + 4 + slot];
        float4 ra = h4[(size_t)ca.x * 16 + q];
        float4 rb = h4[(size_t)cb.x * 16 + q];
        float t0 = rd.x * ra.x + rd.y * ra.y + rd.z * ra.z + rd.w * ra.w;
        float t1 = rd.x * rb.x + rd.y * rb.y + rd.z * rb.z + rd.w * rb.w;
#pragma unroll
        for (int off = 1; off < 16; off <<= 1) {
            t0 += __shfl_xor(t0, off);
            t1 += __shfl_xor(t1, off);
        }
        if (q == 0) { out[ca.y] = t0; out[cb.y] = t1; }
    }
    for (; p + 4 <= p1; p += 4) {
        int2 ca = col2[p + slot];
        float4 ra = h4[(size_t)ca.x * 16 + q];
        float t0 = rd.x * ra.x + rd.y * ra.y + rd.z * ra.z + rd.w * ra.w;
#pragma unroll
        for (int off = 1; off < 16; off <<= 1) t0 += __shfl_xor(t0, off);
        if (q == 0) out[ca.y] = t0;
    }
    int rem = p1 - p;  // 0..3
    if (slot < rem) {
        int2 ca = col2[p + slot];
        float4 ra = h4[(size_t)ca.x * 16 + q];
        float t0 = rd.x * ra.x + rd.y * ra.y + rd.z * ra.z + rd.w * ra.w;
#pragma unroll
        for (int off = 1; off < 16; off <<= 1) t0 += __shfl_xor(t0, off);
        if (q == 0) out[ca.y] = t0;
    }
}

extern "C" void kernel_launch(void* const* d_in, const int* in_sizes, int n_in,
                              void* d_out, int out_size, void* d_ws, size_t ws_size,
                              hipStream_t stream) {
    const float* x  = (const float*)d_in[0];
    const int* ei   = (const int*)d_in[1];   // int32 (harness converts ints)
    const float* W1 = (const float*)d_in[2];
    const float* b1 = (const float*)d_in[3];
    const float* W2 = (const float*)d_in[4];
    const float* b2 = (const float*)d_in[5];
    float* out = (float*)d_out;

    const int N = in_sizes[0] / 128;   // 50000
    const int E = in_sizes[1] / 2;     // 800000
    const int* src = ei;
    const int* dst = ei + E;

    // ---- workspace ----
    // floats: dinv[50176] | bufA[N*128] | bufB[N*128]
    // ints:   cnt[N] | incl[N] | rowptr[N+2] | cursor[N] | bsum[256] | col2[E] (int2)
    float* ws   = (float*)d_ws;
    float* dinv = ws;
    float* bufA = ws + 50176;
    float* bufB = bufA + (size_t)N * 128;
    float* hs1  = bufA;
    float* agg1 = bufB;
    float* g2s  = bufA;
    float* agg2 = bufA + (size_t)N * 64;

    int* ibase  = (int*)(bufB + (size_t)N * 128);
    int* cnt    = ibase;
    int* incl   = cnt + N;
    int* rowptr = incl + N;
    int* cursor = rowptr + (N + 2);    // N+2 keeps following offsets even (int2 align)
    int* bsum   = cursor + N;
    int2* col2  = (int2*)(bsum + 256);

    const int B = 256;
    const int NB = (N + 255) / 256;   // 196
    const unsigned nodeBlocks = (unsigned)(((size_t)N * 64 + 255) / 256);

    // ---- CSR build + dinv ----
    hipMemsetAsync(cnt, 0, (size_t)N * sizeof(int), stream);
    cnt_k<<<(E / 4 + B - 1) / B, B, 0, stream>>>(dst, cnt, E);
    scan1_k<<<NB, 256, 0, stream>>>(cnt, incl, bsum, N);
    scan23_k<<<NB, 256, 0, stream>>>(cnt, incl, bsum, rowptr, cursor, dinv, N, E, NB);
    fill_col2_k<<<(E + B - 1) / B, B, 0, stream>>>(src, dst, cursor, col2, E);

    // ---- layer 1: hs1 = (x@W1)*dinv ; agg1 = pull + b1 ----
    gemm_k128<128, false><<<(N + 63) / 64, 256, 0, stream>>>(x, W1, dinv, hs1, N);
    pull128_k<<<nodeBlocks, 256, 0, stream>>>(rowptr, col2, (const float4*)hs1, dinv,
                                              (const float4*)b1, (float4*)agg1, N);

    // ---- layer 2: g2s = (relu(agg1)@W2)*dinv ; agg2 = pull + b2 ----
    gemm_k128<64, true><<<(N + 63) / 64, 256, 0, stream>>>(agg1, W2, dinv, g2s, N);
    pull64_k<<<nodeBlocks, 256, 0, stream>>>(rowptr, col2, (const float4*)g2s, dinv,
                                             (const float4*)b2, (float4*)agg2, N);

    // ---- edge logits (CSR order, dst row amortized) ----
    logits_csr_k<<<nodeBlocks, 256, 0, stream>>>(rowptr, col2, (const float4*)agg2, out, N);
}

// Round 9
// 258.879 us; speedup vs baseline: 1.1416x; 1.0737x over previous
//
#include <hip/hip_runtime.h>
#include <hip/hip_bf16.h>

// ---------------------------------------------------------------------------
// GCN 2-layer + edge dot logits, CSR-pull aggregation.
// agg[d] = dinv[d] * ( sum_{s in in(d)} hs[s] + hs[d] ) + b,  hs = (A@W)*dinv[row]
// Round 9: fuse {fill_col2 + GEMM1} into one launch (independent stages),
// persistent grid-stride pull/logits kernels. Gathers are at the ~3.6 TB/s
// L2-fill floor (FETCH 186MB < 8x25.6MB one-stream-per-XCD bound) -- untouched.
// ---------------------------------------------------------------------------

__global__ void cnt_k(const int* __restrict__ dst, int* __restrict__ cnt, int E) {
    int t = blockIdx.x * blockDim.x + threadIdx.x;
    int e = t * 4;
    if (e + 4 <= E) {
        int4 d4 = *reinterpret_cast<const int4*>(dst + e);
        atomicAdd(&cnt[d4.x], 1);
        atomicAdd(&cnt[d4.y], 1);
        atomicAdd(&cnt[d4.z], 1);
        atomicAdd(&cnt[d4.w], 1);
    } else {
        for (int i = e; i < E; i++) atomicAdd(&cnt[dst[i]], 1);
    }
}

__global__ void scan1_k(const int* __restrict__ cnt, int* __restrict__ incl,
                        int* __restrict__ bsum, int N) {
    __shared__ int sh[256];
    int i = blockIdx.x * 256 + threadIdx.x;
    int v = (i < N) ? cnt[i] : 0;
    sh[threadIdx.x] = v;
    __syncthreads();
#pragma unroll
    for (int off = 1; off < 256; off <<= 1) {
        int t = (threadIdx.x >= off) ? sh[threadIdx.x - off] : 0;
        __syncthreads();
        sh[threadIdx.x] += t;
        __syncthreads();
    }
    if (i < N) incl[i] = sh[threadIdx.x];
    if (threadIdx.x == 255) bsum[blockIdx.x] = sh[255];
}

// fused scan2+scan3: every block rescans bsum in LDS, then elementwise writeback.
__global__ __launch_bounds__(256) void scan23_k(const int* __restrict__ cnt,
                                                const int* __restrict__ incl,
                                                const int* __restrict__ bsum,
                                                int* __restrict__ rowptr,
                                                int* __restrict__ cursor,
                                                float* __restrict__ dinv,
                                                int N, int E, int NB) {
    __shared__ int sh[256];
    __shared__ int blockOff;
    int v = (threadIdx.x < NB) ? bsum[threadIdx.x] : 0;
    sh[threadIdx.x] = v;
    __syncthreads();
#pragma unroll
    for (int off = 1; off < 256; off <<= 1) {
        int t = (threadIdx.x >= off) ? sh[threadIdx.x - off] : 0;
        __syncthreads();
        sh[threadIdx.x] += t;
        __syncthreads();
    }
    if (threadIdx.x == blockIdx.x) blockOff = sh[threadIdx.x] - v;  // exclusive
    __syncthreads();
    int i = blockIdx.x * 256 + threadIdx.x;
    if (i < N) {
        int c = cnt[i];
        int excl = incl[i] - c + blockOff;
        rowptr[i] = excl;
        cursor[i] = excl;
        dinv[i] = rsqrtf(1.0f + (float)c);  // +1 self-loop
    }
    if (i == 0) rowptr[N] = E;
}

// ---------------------------------------------------------------------------
// FUSED: blocks [0,gemmBlocks) run GEMM1 (x@W1 * dinv, BN=128, no relu);
// blocks [gemmBlocks, ...) scatter edges into CSR (packed int2 {src,eid}).
// Both depend only on scan23; mutually independent -> overlap in one launch.
// ---------------------------------------------------------------------------
__global__ __launch_bounds__(256) void gemm1_fill_k(const float* __restrict__ A,
                                                    const float* __restrict__ W,
                                                    const float* __restrict__ dscale,
                                                    float* __restrict__ Out, int M,
                                                    const int* __restrict__ src,
                                                    const int* __restrict__ dst,
                                                    int* __restrict__ cursor,
                                                    int2* __restrict__ col2, int E,
                                                    int gemmBlocks) {
    constexpr int K = 128, BM = 64, BK = 16, BN = 128, TN = 8;
    __shared__ float As[BK][BM + 4];
    __shared__ float Bs[BK][BN];

    if ((int)blockIdx.x >= gemmBlocks) {
        // ---- CSR fill branch ----
        int t = ((int)blockIdx.x - gemmBlocks) * 256 + threadIdx.x;
        int e = t * 4;
        if (e + 4 <= E) {
            int4 s4 = *reinterpret_cast<const int4*>(src + e);
            int4 d4 = *reinterpret_cast<const int4*>(dst + e);
            int p0 = atomicAdd(&cursor[d4.x], 1);
            col2[p0] = make_int2(s4.x, e + 0);
            int p1 = atomicAdd(&cursor[d4.y], 1);
            col2[p1] = make_int2(s4.y, e + 1);
            int p2 = atomicAdd(&cursor[d4.z], 1);
            col2[p2] = make_int2(s4.z, e + 2);
            int p3 = atomicAdd(&cursor[d4.w], 1);
            col2[p3] = make_int2(s4.w, e + 3);
        } else {
            for (int i = e; i < E; i++) {
                int pos = atomicAdd(&cursor[dst[i]], 1);
                col2[pos] = make_int2(src[i], i);
            }
        }
        return;
    }

    // ---- GEMM branch ----
    const int tid = threadIdx.x;
    const int tx = tid & 15, ty = tid >> 4;
    const int row0 = blockIdx.x * BM;

    float acc[4][TN];
#pragma unroll
    for (int m = 0; m < 4; m++)
#pragma unroll
        for (int j = 0; j < TN; j++) acc[m][j] = 0.0f;

    const int ar = tid >> 2;
    const int ak = (tid & 3) * 4;

    for (int kt = 0; kt < K; kt += BK) {
        float4 av = make_float4(0.f, 0.f, 0.f, 0.f);
        int grow = row0 + ar;
        if (grow < M)
            av = *reinterpret_cast<const float4*>(A + (size_t)grow * K + kt + ak);
        As[ak + 0][ar] = av.x; As[ak + 1][ar] = av.y;
        As[ak + 2][ar] = av.z; As[ak + 3][ar] = av.w;

#pragma unroll
        for (int b = 0; b < 2; b++) {
            int f = b * 256 + tid;
            int brow = (f * 4) / BN;
            int bcol = (f * 4) % BN;
            float4 bv = *reinterpret_cast<const float4*>(W + (size_t)(kt + brow) * BN + bcol);
            *reinterpret_cast<float4*>(&Bs[brow][bcol]) = bv;
        }
        __syncthreads();

#pragma unroll
        for (int k = 0; k < BK; k++) {
            float4 a4 = *reinterpret_cast<const float4*>(&As[k][ty * 4]);
            float a[4] = {a4.x, a4.y, a4.z, a4.w};
            float bb[TN];
#pragma unroll
            for (int j4 = 0; j4 < TN / 4; j4++) {
                float4 b4 = *reinterpret_cast<const float4*>(&Bs[k][tx * TN + j4 * 4]);
                bb[j4 * 4 + 0] = b4.x; bb[j4 * 4 + 1] = b4.y;
                bb[j4 * 4 + 2] = b4.z; bb[j4 * 4 + 3] = b4.w;
            }
#pragma unroll
            for (int m = 0; m < 4; m++)
#pragma unroll
                for (int j = 0; j < TN; j++) acc[m][j] = fmaf(a[m], bb[j], acc[m][j]);
        }
        __syncthreads();
    }

#pragma unroll
    for (int m = 0; m < 4; m++) {
        int gr = row0 + ty * 4 + m;
        if (gr < M) {
            float dv = dscale[gr];
#pragma unroll
            for (int j4 = 0; j4 < TN / 4; j4++) {
                float4 o = make_float4(acc[m][j4 * 4 + 0] * dv, acc[m][j4 * 4 + 1] * dv,
                                       acc[m][j4 * 4 + 2] * dv, acc[m][j4 * 4 + 3] * dv);
                *reinterpret_cast<float4*>(Out + (size_t)gr * BN + tx * TN + j4 * 4) = o;
            }
        }
    }
}

// ---------------------------------------------------------------------------
// GEMM2 (round-5, k-major As): g2s = relu(agg1)@W2 * dinv. BN=64.
// ---------------------------------------------------------------------------
__global__ __launch_bounds__(256) void gemm2_k(const float* __restrict__ A,
                                               const float* __restrict__ W,
                                               const float* __restrict__ dscale,
                                               float* __restrict__ Out, int M) {
    constexpr int K = 128, BM = 64, BK = 16, BN = 64, TN = 4;
    __shared__ float As[BK][BM + 4];
    __shared__ float Bs[BK][BN];

    const int tid = threadIdx.x;
    const int tx = tid & 15, ty = tid >> 4;
    const int row0 = blockIdx.x * BM;

    float acc[4][TN];
#pragma unroll
    for (int m = 0; m < 4; m++)
#pragma unroll
        for (int j = 0; j < TN; j++) acc[m][j] = 0.0f;

    const int ar = tid >> 2;
    const int ak = (tid & 3) * 4;

    for (int kt = 0; kt < K; kt += BK) {
        float4 av = make_float4(0.f, 0.f, 0.f, 0.f);
        int grow = row0 + ar;
        if (grow < M)
            av = *reinterpret_cast<const float4*>(A + (size_t)grow * K + kt + ak);
        av.x = fmaxf(av.x, 0.f); av.y = fmaxf(av.y, 0.f);
        av.z = fmaxf(av.z, 0.f); av.w = fmaxf(av.w, 0.f);
        As[ak + 0][ar] = av.x; As[ak + 1][ar] = av.y;
        As[ak + 2][ar] = av.z; As[ak + 3][ar] = av.w;

        {
            int f = tid;
            int brow = (f * 4) / BN;
            int bcol = (f * 4) % BN;
            float4 bv = *reinterpret_cast<const float4*>(W + (size_t)(kt + brow) * BN + bcol);
            *reinterpret_cast<float4*>(&Bs[brow][bcol]) = bv;
        }
        __syncthreads();

#pragma unroll
        for (int k = 0; k < BK; k++) {
            float4 a4 = *reinterpret_cast<const float4*>(&As[k][ty * 4]);
            float a[4] = {a4.x, a4.y, a4.z, a4.w};
            float4 b4 = *reinterpret_cast<const float4*>(&Bs[k][tx * TN]);
            float bb[TN] = {b4.x, b4.y, b4.z, b4.w};
#pragma unroll
            for (int m = 0; m < 4; m++)
#pragma unroll
                for (int j = 0; j < TN; j++) acc[m][j] = fmaf(a[m], bb[j], acc[m][j]);
        }
        __syncthreads();
    }

#pragma unroll
    for (int m = 0; m < 4; m++) {
        int gr = row0 + ty * 4 + m;
        if (gr < M) {
            float dv = dscale[gr];
            float4 o = make_float4(acc[m][0] * dv, acc[m][1] * dv,
                                   acc[m][2] * dv, acc[m][3] * dv);
            *reinterpret_cast<float4*>(Out + (size_t)gr * BN + tx * TN) = o;
        }
    }
}

// ---------------------------------------------------------------------------
// pull128: persistent, one wave per node per iteration; 2 slots x 32 lanes.
// ---------------------------------------------------------------------------
__global__ __launch_bounds__(256) void pull128_k(const int* __restrict__ rowptr,
                                                 const int2* __restrict__ col2,
                                                 const float4* __restrict__ hs4,
                                                 const float* __restrict__ dinv,
                                                 const float4* __restrict__ bias4,
                                                 float4* __restrict__ out4, int N) {
    int wid = (int)((blockIdx.x * blockDim.x + threadIdx.x) >> 6);
    int nw = (int)((gridDim.x * blockDim.x) >> 6);
    int lane = threadIdx.x & 63;
    int q = lane & 31, slot = lane >> 5;

    for (int v = wid; v < N; v += nw) {
        int p0 = rowptr[v], p1 = rowptr[v + 1];

        float4 acc = make_float4(0.f, 0.f, 0.f, 0.f);
        if (slot == 0) acc = hs4[(size_t)v * 32 + q];  // self row

        int p = p0;
        for (; p + 8 <= p1; p += 8) {
            int ia = col2[p + slot].x, ib = col2[p + 2 + slot].x;
            int ic = col2[p + 4 + slot].x, id = col2[p + 6 + slot].x;
            float4 a = hs4[(size_t)ia * 32 + q];
            float4 b = hs4[(size_t)ib * 32 + q];
            float4 c = hs4[(size_t)ic * 32 + q];
            float4 d = hs4[(size_t)id * 32 + q];
            acc.x += (a.x + b.x) + (c.x + d.x);
            acc.y += (a.y + b.y) + (c.y + d.y);
            acc.z += (a.z + b.z) + (c.z + d.z);
            acc.w += (a.w + b.w) + (c.w + d.w);
        }
        for (; p + 2 <= p1; p += 2) {
            int ia = col2[p + slot].x;
            float4 a = hs4[(size_t)ia * 32 + q];
            acc.x += a.x; acc.y += a.y; acc.z += a.z; acc.w += a.w;
        }
        if (p < p1 && slot == 0) {
            float4 a = hs4[(size_t)col2[p].x * 32 + q];
            acc.x += a.x; acc.y += a.y; acc.z += a.z; acc.w += a.w;
        }

        acc.x += __shfl_xor(acc.x, 32);
        acc.y += __shfl_xor(acc.y, 32);
        acc.z += __shfl_xor(acc.z, 32);
        acc.w += __shfl_xor(acc.w, 32);

        if (slot == 0) {
            float dv = dinv[v];
            float4 bv = bias4[q];
            out4[(size_t)v * 32 + q] = make_float4(fmaf(acc.x, dv, bv.x), fmaf(acc.y, dv, bv.y),
                                                   fmaf(acc.z, dv, bv.z), fmaf(acc.w, dv, bv.w));
        }
    }
}

// ---------------------------------------------------------------------------
// pull64: persistent, 4 slots x 16 lanes.
// ---------------------------------------------------------------------------
__global__ __launch_bounds__(256) void pull64_k(const int* __restrict__ rowptr,
                                                const int2* __restrict__ col2,
                                                const float4* __restrict__ hs4,
                                                const float* __restrict__ dinv,
                                                const float4* __restrict__ bias4,
                                                float4* __restrict__ out4, int N) {
    int wid = (int)((blockIdx.x * blockDim.x + threadIdx.x) >> 6);
    int nw = (int)((gridDim.x * blockDim.x) >> 6);
    int lane = threadIdx.x & 63;
    int q = lane & 15, slot = lane >> 4;

    for (int v = wid; v < N; v += nw) {
        int p0 = rowptr[v], p1 = rowptr[v + 1];

        float4 acc = make_float4(0.f, 0.f, 0.f, 0.f);
        if (slot == 0) acc = hs4[(size_t)v * 16 + q];  // self row

        int p = p0;
        for (; p + 8 <= p1; p += 8) {
            int ia = col2[p + slot].x, ib = col2[p + 4 + slot].x;
            float4 a = hs4[(size_t)ia * 16 + q];
            float4 b = hs4[(size_t)ib * 16 + q];
            acc.x += a.x + b.x; acc.y += a.y + b.y;
            acc.z += a.z + b.z; acc.w += a.w + b.w;
        }
        for (; p + 4 <= p1; p += 4) {
            float4 a = hs4[(size_t)col2[p + slot].x * 16 + q];
            acc.x += a.x; acc.y += a.y; acc.z += a.z; acc.w += a.w;
        }
        int rem = p1 - p;  // 0..3
        if (slot < rem) {
            float4 a = hs4[(size_t)col2[p + slot].x * 16 + q];
            acc.x += a.x; acc.y += a.y; acc.z += a.z; acc.w += a.w;
        }

#pragma unroll
        for (int off = 16; off <= 32; off <<= 1) {
            acc.x += __shfl_xor(acc.x, off);
            acc.y += __shfl_xor(acc.y, off);
            acc.z += __shfl_xor(acc.z, off);
            acc.w += __shfl_xor(acc.w, off);
        }

        if (slot == 0) {
            float dv = dinv[v];
            float4 bv = bias4[q];
            out4[(size_t)v * 16 + q] = make_float4(fmaf(acc.x, dv, bv.x), fmaf(acc.y, dv, bv.y),
                                                   fmaf(acc.z, dv, bv.z), fmaf(acc.w, dv, bv.w));
        }
    }
}

// ---------------------------------------------------------------------------
// logits: persistent CSR; dst row wave-resident, src rows gathered.
// ---------------------------------------------------------------------------
__global__ __launch_bounds__(256) void logits_csr_k(const int* __restrict__ rowptr,
                                                    const int2* __restrict__ col2,
                                                    const float4* __restrict__ h4,
                                                    float* __restrict__ out, int N) {
    int wid = (int)((blockIdx.x * blockDim.x + threadIdx.x) >> 6);
    int nw = (int)((gridDim.x * blockDim.x) >> 6);
    int lane = threadIdx.x & 63;
    int q = lane & 15, slot = lane >> 4;

    for (int v = wid; v < N; v += nw) {
        int p0 = rowptr[v], p1 = rowptr[v + 1];
        if (p0 == p1) continue;

        float4 rd = h4[(size_t)v * 16 + q];  // dst row

        int p = p0;
        for (; p + 8 <= p1; p += 8) {
            int2 ca = col2[p + slot], cb = col2[p + 4 + slot];
            float4 ra = h4[(size_t)ca.x * 16 + q];
            float4 rb = h4[(size_t)cb.x * 16 + q];
            float t0 = rd.x * ra.x + rd.y * ra.y + rd.z * ra.z + rd.w * ra.w;
            float t1 = rd.x * rb.x + rd.y * rb.y + rd.z * rb.z + rd.w * rb.w;
#pragma unroll
            for (int off = 1; off < 16; off <<= 1) {
                t0 += __shfl_xor(t0, off);
                t1 += __shfl_xor(t1, off);
            }
            if (q == 0) { out[ca.y] = t0; out[cb.y] = t1; }
        }
        for (; p + 4 <= p1; p += 4) {
            int2 ca = col2[p + slot];
            float4 ra = h4[(size_t)ca.x * 16 + q];
            float t0 = rd.x * ra.x + rd.y * ra.y + rd.z * ra.z + rd.w * ra.w;
#pragma unroll
            for (int off = 1; off < 16; off <<= 1) t0 += __shfl_xor(t0, off);
            if (q == 0) out[ca.y] = t0;
        }
        int rem = p1 - p;  // 0..3
        if (slot < rem) {
            int2 ca = col2[p + slot];
            float4 ra = h4[(size_t)ca.x * 16 + q];
            float t0 = rd.x * ra.x + rd.y * ra.y + rd.z * ra.z + rd.w * ra.w;
#pragma unroll
            for (int off = 1; off < 16; off <<= 1) t0 += __shfl_xor(t0, off);
            if (q == 0) out[ca.y] = t0;
        }
    }
}

extern "C" void kernel_launch(void* const* d_in, const int* in_sizes, int n_in,
                              void* d_out, int out_size, void* d_ws, size_t ws_size,
                              hipStream_t stream) {
    const float* x  = (const float*)d_in[0];
    const int* ei   = (const int*)d_in[1];   // int32 (harness converts ints)
    const float* W1 = (const float*)d_in[2];
    const float* b1 = (const float*)d_in[3];
    const float* W2 = (const float*)d_in[4];
    const float* b2 = (const float*)d_in[5];
    float* out = (float*)d_out;

    const int N = in_sizes[0] / 128;   // 50000
    const int E = in_sizes[1] / 2;     // 800000
    const int* src = ei;
    const int* dst = ei + E;

    // ---- workspace ----
    // floats: dinv[50176] | bufA[N*128] | bufB[N*128]
    // ints:   cnt[N] | incl[N] | rowptr[N+2] | cursor[N] | bsum[256] | col2[E] (int2)
    float* ws   = (float*)d_ws;
    float* dinv = ws;
    float* bufA = ws + 50176;
    float* bufB = bufA + (size_t)N * 128;
    float* hs1  = bufA;
    float* agg1 = bufB;
    float* g2s  = bufA;
    float* agg2 = bufA + (size_t)N * 64;

    int* ibase  = (int*)(bufB + (size_t)N * 128);
    int* cnt    = ibase;
    int* incl   = cnt + N;
    int* rowptr = incl + N;
    int* cursor = rowptr + (N + 2);    // keeps later offsets 8B-aligned
    int* bsum   = cursor + N;
    int2* col2  = (int2*)(bsum + 256);

    const int B = 256;
    const int NB = (N + 255) / 256;   // 196
    const unsigned persBlocks = 2048;

    // ---- CSR count + scan ----
    hipMemsetAsync(cnt, 0, (size_t)N * sizeof(int), stream);
    cnt_k<<<(E / 4 + B - 1) / B, B, 0, stream>>>(dst, cnt, E);
    scan1_k<<<NB, 256, 0, stream>>>(cnt, incl, bsum, N);
    scan23_k<<<NB, 256, 0, stream>>>(cnt, incl, bsum, rowptr, cursor, dinv, N, E, NB);

    // ---- fused: GEMM1 (hs1 = x@W1*dinv) + CSR fill (col2) ----
    {
        int gemmBlocks = (N + 63) / 64;              // 782
        int fillBlocks = (E / 4 + B - 1) / B;        // 782
        gemm1_fill_k<<<gemmBlocks + fillBlocks, 256, 0, stream>>>(
            x, W1, dinv, hs1, N, src, dst, cursor, col2, E, gemmBlocks);
    }

    // ---- layer 1 pull ----
    pull128_k<<<persBlocks, 256, 0, stream>>>(rowptr, col2, (const float4*)hs1, dinv,
                                              (const float4*)b1, (float4*)agg1, N);

    // ---- layer 2 ----
    gemm2_k<<<(N + 63) / 64, 256, 0, stream>>>(agg1, W2, dinv, g2s, N);
    pull64_k<<<persBlocks, 256, 0, stream>>>(rowptr, col2, (const float4*)g2s, dinv,
                                             (const float4*)b2, (float4*)agg2, N);

    // ---- edge logits ----
    logits_csr_k<<<persBlocks, 256, 0, stream>>>(rowptr, col2, (const float4*)agg2, out, N);
}